// Round 4
// baseline (303.085 us; speedup 1.0000x reference)
//
#include <hip/hip_runtime.h>
#include <math.h>

#define N_NODES 100000
#define N_EDGES 1600000
#define DIM 64

#define SCAN_BS   256
#define SCAN_EPB  1024
#define SCAN_NBLK ((N_NODES + SCAN_EPB - 1) / SCAN_EPB)   // 98

// sigmoid(s*w+b) = rcp(1 + exp2(s*(-w*log2e) + (-b*log2e)))
__device__ __forceinline__ float fast_gate(float s, float wl, float bl2) {
    return __builtin_amdgcn_rcpf(1.0f + __builtin_amdgcn_exp2f(fmaf(s, wl, bl2)));
}

// ---------------------------------------------------------------------------
// 1) Histogram of destination rows (2 edges/thread).
// ---------------------------------------------------------------------------
__global__ __launch_bounds__(256) void histo_kernel(
    const int* __restrict__ edge, int* __restrict__ cnt)
{
    int t = blockIdx.x * 256 + threadIdx.x;
    if (t < N_EDGES / 2) {
        int2 rr = ((const int2*)edge)[t];
        atomicAdd(&cnt[rr.x], 1);
        atomicAdd(&cnt[rr.y], 1);
    }
}

// ---------------------------------------------------------------------------
// 2a) Per-block reduce of cnt.
// ---------------------------------------------------------------------------
__global__ __launch_bounds__(SCAN_BS) void scan_reduce_kernel(
    const int* __restrict__ cnt, int* __restrict__ bsum)
{
    __shared__ int ls[SCAN_BS];
    int base = blockIdx.x * SCAN_EPB;
    int s = 0;
    #pragma unroll
    for (int i = 0; i < 4; ++i) {
        int idx = base + threadIdx.x + i * SCAN_BS;
        s += (idx < N_NODES) ? cnt[idx] : 0;
    }
    ls[threadIdx.x] = s;
    __syncthreads();
    for (int o = SCAN_BS / 2; o > 0; o >>= 1) {
        if (threadIdx.x < o) ls[threadIdx.x] += ls[threadIdx.x + o];
        __syncthreads();
    }
    if (threadIdx.x == 0) bsum[blockIdx.x] = ls[0];
}

// ---------------------------------------------------------------------------
// 2b) Exclusive scan of the 98 block sums.
// ---------------------------------------------------------------------------
__global__ __launch_bounds__(128) void scan_top_kernel(int* __restrict__ bsum)
{
    __shared__ int ls[SCAN_NBLK];
    if (threadIdx.x < SCAN_NBLK) ls[threadIdx.x] = bsum[threadIdx.x];
    __syncthreads();
    if (threadIdx.x == 0) {
        int run = 0;
        for (int i = 0; i < SCAN_NBLK; ++i) { int t = ls[i]; ls[i] = run; run += t; }
    }
    __syncthreads();
    if (threadIdx.x < SCAN_NBLK) bsum[threadIdx.x] = ls[threadIdx.x];
}

// ---------------------------------------------------------------------------
// 2c) Per-block rescan -> off[], cursor[].
// ---------------------------------------------------------------------------
__global__ __launch_bounds__(SCAN_BS) void scan_down_kernel(
    const int* __restrict__ cnt, const int* __restrict__ bsum,
    int* __restrict__ off, int* __restrict__ cursor)
{
    __shared__ int ls[SCAN_BS];
    const int tid  = threadIdx.x;
    const int base = blockIdx.x * SCAN_EPB;

    int v[4]; int tsum = 0;
    #pragma unroll
    for (int i = 0; i < 4; ++i) {
        int idx = base + tid * 4 + i;
        v[i] = (idx < N_NODES) ? cnt[idx] : 0;
        tsum += v[i];
    }
    ls[tid] = tsum;
    __syncthreads();
    for (int o = 1; o < SCAN_BS; o <<= 1) {
        int t = (tid >= o) ? ls[tid - o] : 0;
        __syncthreads();
        ls[tid] += t;
        __syncthreads();
    }
    int run = bsum[blockIdx.x] + ls[tid] - tsum;
    #pragma unroll
    for (int i = 0; i < 4; ++i) {
        int idx = base + tid * 4 + i;
        if (idx < N_NODES) { off[idx] = run; cursor[idx] = run; }
        run += v[i];
    }
}

// ---------------------------------------------------------------------------
// 3) Scatter cols into CSR order (2 edges/thread, 4B stores).
// ---------------------------------------------------------------------------
__global__ __launch_bounds__(256) void scatter_kernel(
    const int* __restrict__ edge, int* __restrict__ cursor,
    int* __restrict__ scol)
{
    int t = blockIdx.x * 256 + threadIdx.x;
    if (t >= N_EDGES / 2) return;
    int2 rr = ((const int2*)edge)[t];
    int2 cc = ((const int2*)(edge + N_EDGES))[t];
    int p0 = atomicAdd(&cursor[rr.x], 1);
    scol[p0] = cc.x;
    int p1 = atomicAdd(&cursor[rr.y], 1);
    scol[p1] = cc.y;
}

// ---------------------------------------------------------------------------
// 4) Per-node gather: wave = node, lane l -> edge-group (l>>4),
//    feature quad ((l&15)*4). One dwordx4 gather covers 4 edges x 256B.
//    Cross-group reduce via shfl_xor(16|32), then mean+Linear+GELU.
// ---------------------------------------------------------------------------
__global__ __launch_bounds__(256) void node_kernel(
    const float* __restrict__ x,    const float* __restrict__ curv,
    const int*   __restrict__ cnt,  const int* __restrict__ off,
    const int*   __restrict__ scol,
    const float* __restrict__ Wc,   const float* __restrict__ bc,
    const float* __restrict__ Wl,   const float* __restrict__ bl,
    float* __restrict__ out)
{
    __shared__ float Ws[64][65];
    __shared__ float ms[4][64];

    const int tid = threadIdx.x;
    #pragma unroll
    for (int i = tid; i < DIM * DIM; i += 256)
        Ws[i >> 6][i & 63] = Wl[i];

    const int sub  = tid >> 6;          // wave (node) within block
    const int lane = tid & 63;
    const int eg   = lane >> 4;         // edge group 0..3
    const int fg   = (lane & 15) << 2;  // feature base
    const int node = blockIdx.x * 4 + sub;   // grid exact: always < N_NODES

    const int   deg   = cnt[node];
    const int   start = off[node];
    const float cn    = curv[node];

    const float L2E = 1.44269504088896340736f;
    const float4 wc4 = *(const float4*)&Wc[fg];
    const float4 bc4 = *(const float4*)&bc[fg];
    const float wl0 = -wc4.x * L2E, wl1 = -wc4.y * L2E,
                wl2 = -wc4.z * L2E, wl3 = -wc4.w * L2E;
    const float bl0 = -bc4.x * L2E, bl1 = -bc4.y * L2E,
                bl2_ = -bc4.z * L2E, bl3 = -bc4.w * L2E;

    float a0 = 0.f, a1 = 0.f, a2 = 0.f, a3 = 0.f;

    int k = eg;
    for (; k + 4 < deg; k += 8) {              // 2 edges per lane per iter
        int c0 = scol[start + k];
        int c1 = scol[start + k + 4];
        float s0 = fabsf(cn - curv[c0]);
        float s1 = fabsf(cn - curv[c1]);
        float4 x0 = *(const float4*)&x[((size_t)c0 << 6) + fg];
        float4 x1 = *(const float4*)&x[((size_t)c1 << 6) + fg];
        a0 = fmaf(x0.x, fast_gate(s0, wl0, bl0),  a0);
        a1 = fmaf(x0.y, fast_gate(s0, wl1, bl1),  a1);
        a2 = fmaf(x0.z, fast_gate(s0, wl2, bl2_), a2);
        a3 = fmaf(x0.w, fast_gate(s0, wl3, bl3),  a3);
        a0 = fmaf(x1.x, fast_gate(s1, wl0, bl0),  a0);
        a1 = fmaf(x1.y, fast_gate(s1, wl1, bl1),  a1);
        a2 = fmaf(x1.z, fast_gate(s1, wl2, bl2_), a2);
        a3 = fmaf(x1.w, fast_gate(s1, wl3, bl3),  a3);
    }
    if (k < deg) {
        int c0 = scol[start + k];
        float s0 = fabsf(cn - curv[c0]);
        float4 x0 = *(const float4*)&x[((size_t)c0 << 6) + fg];
        a0 = fmaf(x0.x, fast_gate(s0, wl0, bl0),  a0);
        a1 = fmaf(x0.y, fast_gate(s0, wl1, bl1),  a1);
        a2 = fmaf(x0.z, fast_gate(s0, wl2, bl2_), a2);
        a3 = fmaf(x0.w, fast_gate(s0, wl3, bl3),  a3);
    }

    // sum the 4 edge groups (lanes l, l^16, l^32, l^48)
    a0 += __shfl_xor(a0, 16); a0 += __shfl_xor(a0, 32);
    a1 += __shfl_xor(a1, 16); a1 += __shfl_xor(a1, 32);
    a2 += __shfl_xor(a2, 16); a2 += __shfl_xor(a2, 32);
    a3 += __shfl_xor(a3, 16); a3 += __shfl_xor(a3, 32);

    const float inv = __builtin_amdgcn_rcpf(fmaxf((float)deg, 1.0f));
    if (eg == 0)
        *(float4*)&ms[sub][fg] = make_float4(a0 * inv, a1 * inv, a2 * inv, a3 * inv);

    __syncthreads();

    const int d = lane;
    float r = bl[d];
    #pragma unroll
    for (int q = 0; q < DIM; ++q)
        r = fmaf(ms[sub][q], Ws[d][q], r);

    out[(size_t)node * DIM + d] = 0.5f * r * (1.0f + erff(r * 0.70710678118654752f));
}

// ---------------------------------------------------------------------------
extern "C" void kernel_launch(void* const* d_in, const int* in_sizes, int n_in,
                              void* d_out, int out_size, void* d_ws, size_t ws_size,
                              hipStream_t stream) {
    const float* x    = (const float*)d_in[0];
    const float* curv = (const float*)d_in[1];
    const float* Wc   = (const float*)d_in[2];
    const float* bc   = (const float*)d_in[3];
    const float* Wl   = (const float*)d_in[4];
    const float* bl   = (const float*)d_in[5];
    const int*   edge = (const int*)d_in[6];

    float* out = (float*)d_out;

    int* cnt    = (int*)d_ws;              // N
    int* off    = cnt + N_NODES;           // N
    int* cursor = off + N_NODES;           // N
    int* bsum   = cursor + N_NODES;        // 128
    int* scol   = bsum + 128;              // E (6.4 MB)

    hipMemsetAsync(cnt, 0, N_NODES * sizeof(int), stream);

    const int hblk = (N_EDGES / 2 + 255) / 256;   // 3125
    histo_kernel<<<hblk, 256, 0, stream>>>(edge, cnt);
    scan_reduce_kernel<<<SCAN_NBLK, SCAN_BS, 0, stream>>>(cnt, bsum);
    scan_top_kernel<<<1, 128, 0, stream>>>(bsum);
    scan_down_kernel<<<SCAN_NBLK, SCAN_BS, 0, stream>>>(cnt, bsum, off, cursor);
    scatter_kernel<<<hblk, 256, 0, stream>>>(edge, cursor, scol);
    node_kernel<<<N_NODES / 4, 256, 0, stream>>>(
        x, curv, cnt, off, scol, Wc, bc, Wl, bl, out);
}

// Round 5
// 200.207 us; speedup vs baseline: 1.5139x; 1.5139x over previous
//
#include <hip/hip_runtime.h>
#include <math.h>

#define N_NODES 100000
#define N_EDGES 1600000
#define DIM 64
#define CPAD 16      // counters padded to one per 64B cache line

#define SCAN_BS   256
#define SCAN_EPB  1024
#define SCAN_NBLK ((N_NODES + SCAN_EPB - 1) / SCAN_EPB)   // 98

// sigmoid(s*w+b) = rcp(1 + exp2(s*(-w*log2e) + (-b*log2e)))
__device__ __forceinline__ float fast_gate(float s, float wl, float bl2) {
    return __builtin_amdgcn_rcpf(1.0f + __builtin_amdgcn_exp2f(fmaf(s, wl, bl2)));
}

// ---------------------------------------------------------------------------
// 1) Fused histogram + rank: rank[e] = old count of row[e].
//    Counters padded (64B apart) to minimize same-line atomic serialization.
// ---------------------------------------------------------------------------
__global__ __launch_bounds__(256) void rank_kernel(
    const int* __restrict__ edge, int* __restrict__ cntp,
    int* __restrict__ rank)
{
    int e = blockIdx.x * 256 + threadIdx.x;
    if (e < N_EDGES)
        rank[e] = atomicAdd(&cntp[(size_t)edge[e] * CPAD], 1);
}

// ---------------------------------------------------------------------------
// 2a) Per-block reduce of padded cnt.
// ---------------------------------------------------------------------------
__global__ __launch_bounds__(SCAN_BS) void scan_reduce_kernel(
    const int* __restrict__ cntp, int* __restrict__ bsum)
{
    __shared__ int ls[SCAN_BS];
    int base = blockIdx.x * SCAN_EPB;
    int s = 0;
    #pragma unroll
    for (int i = 0; i < 4; ++i) {
        int idx = base + threadIdx.x + i * SCAN_BS;
        s += (idx < N_NODES) ? cntp[(size_t)idx * CPAD] : 0;
    }
    ls[threadIdx.x] = s;
    __syncthreads();
    for (int o = SCAN_BS / 2; o > 0; o >>= 1) {
        if (threadIdx.x < o) ls[threadIdx.x] += ls[threadIdx.x + o];
        __syncthreads();
    }
    if (threadIdx.x == 0) bsum[blockIdx.x] = ls[0];
}

// ---------------------------------------------------------------------------
// 2b) Exclusive scan of the 98 block sums.
// ---------------------------------------------------------------------------
__global__ __launch_bounds__(128) void scan_top_kernel(int* __restrict__ bsum)
{
    __shared__ int ls[SCAN_NBLK];
    if (threadIdx.x < SCAN_NBLK) ls[threadIdx.x] = bsum[threadIdx.x];
    __syncthreads();
    if (threadIdx.x == 0) {
        int run = 0;
        for (int i = 0; i < SCAN_NBLK; ++i) { int t = ls[i]; ls[i] = run; run += t; }
    }
    __syncthreads();
    if (threadIdx.x < SCAN_NBLK) bsum[threadIdx.x] = ls[threadIdx.x];
}

// ---------------------------------------------------------------------------
// 2c) Per-block rescan -> off[] (exclusive prefix of degrees).
// ---------------------------------------------------------------------------
__global__ __launch_bounds__(SCAN_BS) void scan_down_kernel(
    const int* __restrict__ cntp, const int* __restrict__ bsum,
    int* __restrict__ off)
{
    __shared__ int ls[SCAN_BS];
    const int tid  = threadIdx.x;
    const int base = blockIdx.x * SCAN_EPB;

    int v[4]; int tsum = 0;
    #pragma unroll
    for (int i = 0; i < 4; ++i) {
        int idx = base + tid * 4 + i;
        v[i] = (idx < N_NODES) ? cntp[(size_t)idx * CPAD] : 0;
        tsum += v[i];
    }
    ls[tid] = tsum;
    __syncthreads();
    for (int o = 1; o < SCAN_BS; o <<= 1) {
        int t = (tid >= o) ? ls[tid - o] : 0;
        __syncthreads();
        ls[tid] += t;
        __syncthreads();
    }
    int run = bsum[blockIdx.x] + ls[tid] - tsum;
    #pragma unroll
    for (int i = 0; i < 4; ++i) {
        int idx = base + tid * 4 + i;
        if (idx < N_NODES) off[idx] = run;
        run += v[i];
    }
}

// ---------------------------------------------------------------------------
// 3) Atomic-free scatter: slot = off[row] + rank[e]. All loads coalesced;
//    single scattered 4B store per edge, fire-and-forget.
// ---------------------------------------------------------------------------
__global__ __launch_bounds__(256) void scatter_kernel(
    const int* __restrict__ edge, const int* __restrict__ rank,
    const int* __restrict__ off,  int* __restrict__ scol)
{
    int e = blockIdx.x * 256 + threadIdx.x;
    if (e >= N_EDGES) return;
    int r  = edge[e];
    int c  = edge[N_EDGES + e];
    int rk = rank[e];
    scol[off[r] + rk] = c;
}

// ---------------------------------------------------------------------------
// 4) Per-node gather: wave = node, lane l -> edge-group (l>>4),
//    feature quad ((l&15)*4). One dwordx4 gather covers 4 edges x 256B.
//    Cross-group reduce via shfl_xor(16|32), then mean+Linear+GELU.
// ---------------------------------------------------------------------------
__global__ __launch_bounds__(256) void node_kernel(
    const float* __restrict__ x,    const float* __restrict__ curv,
    const int*   __restrict__ off,  const int* __restrict__ scol,
    const float* __restrict__ Wc,   const float* __restrict__ bc,
    const float* __restrict__ Wl,   const float* __restrict__ bl,
    float* __restrict__ out)
{
    __shared__ float Ws[64][65];
    __shared__ float ms[4][64];

    const int tid = threadIdx.x;
    #pragma unroll
    for (int i = tid; i < DIM * DIM; i += 256)
        Ws[i >> 6][i & 63] = Wl[i];

    const int sub  = tid >> 6;          // wave (node) within block
    const int lane = tid & 63;
    const int eg   = lane >> 4;         // edge group 0..3
    const int fg   = (lane & 15) << 2;  // feature base
    const int node = blockIdx.x * 4 + sub;   // grid exact: always < N_NODES

    const int   start = off[node];
    const int   deg   = ((node < N_NODES - 1) ? off[node + 1] : N_EDGES) - start;
    const float cn    = curv[node];

    const float L2E = 1.44269504088896340736f;
    const float4 wc4 = *(const float4*)&Wc[fg];
    const float4 bc4 = *(const float4*)&bc[fg];
    const float wl0 = -wc4.x * L2E, wl1 = -wc4.y * L2E,
                wl2 = -wc4.z * L2E, wl3 = -wc4.w * L2E;
    const float bl0 = -bc4.x * L2E, bl1 = -bc4.y * L2E,
                bl2_ = -bc4.z * L2E, bl3 = -bc4.w * L2E;

    float a0 = 0.f, a1 = 0.f, a2 = 0.f, a3 = 0.f;

    int k = eg;
    for (; k + 4 < deg; k += 8) {              // 2 edges per lane per iter
        int c0 = scol[start + k];
        int c1 = scol[start + k + 4];
        float s0 = fabsf(cn - curv[c0]);
        float s1 = fabsf(cn - curv[c1]);
        float4 x0 = *(const float4*)&x[((size_t)c0 << 6) + fg];
        float4 x1 = *(const float4*)&x[((size_t)c1 << 6) + fg];
        a0 = fmaf(x0.x, fast_gate(s0, wl0, bl0),  a0);
        a1 = fmaf(x0.y, fast_gate(s0, wl1, bl1),  a1);
        a2 = fmaf(x0.z, fast_gate(s0, wl2, bl2_), a2);
        a3 = fmaf(x0.w, fast_gate(s0, wl3, bl3),  a3);
        a0 = fmaf(x1.x, fast_gate(s1, wl0, bl0),  a0);
        a1 = fmaf(x1.y, fast_gate(s1, wl1, bl1),  a1);
        a2 = fmaf(x1.z, fast_gate(s1, wl2, bl2_), a2);
        a3 = fmaf(x1.w, fast_gate(s1, wl3, bl3),  a3);
    }
    if (k < deg) {
        int c0 = scol[start + k];
        float s0 = fabsf(cn - curv[c0]);
        float4 x0 = *(const float4*)&x[((size_t)c0 << 6) + fg];
        a0 = fmaf(x0.x, fast_gate(s0, wl0, bl0),  a0);
        a1 = fmaf(x0.y, fast_gate(s0, wl1, bl1),  a1);
        a2 = fmaf(x0.z, fast_gate(s0, wl2, bl2_), a2);
        a3 = fmaf(x0.w, fast_gate(s0, wl3, bl3),  a3);
    }

    // sum the 4 edge groups (lanes l, l^16, l^32, l^48)
    a0 += __shfl_xor(a0, 16); a0 += __shfl_xor(a0, 32);
    a1 += __shfl_xor(a1, 16); a1 += __shfl_xor(a1, 32);
    a2 += __shfl_xor(a2, 16); a2 += __shfl_xor(a2, 32);
    a3 += __shfl_xor(a3, 16); a3 += __shfl_xor(a3, 32);

    const float inv = __builtin_amdgcn_rcpf(fmaxf((float)deg, 1.0f));
    if (eg == 0)
        *(float4*)&ms[sub][fg] = make_float4(a0 * inv, a1 * inv, a2 * inv, a3 * inv);

    __syncthreads();

    const int d = lane;
    float r = bl[d];
    #pragma unroll
    for (int q = 0; q < DIM; ++q)
        r = fmaf(ms[sub][q], Ws[d][q], r);

    out[(size_t)node * DIM + d] = 0.5f * r * (1.0f + erff(r * 0.70710678118654752f));
}

// ---------------------------------------------------------------------------
extern "C" void kernel_launch(void* const* d_in, const int* in_sizes, int n_in,
                              void* d_out, int out_size, void* d_ws, size_t ws_size,
                              hipStream_t stream) {
    const float* x    = (const float*)d_in[0];
    const float* curv = (const float*)d_in[1];
    const float* Wc   = (const float*)d_in[2];
    const float* bc   = (const float*)d_in[3];
    const float* Wl   = (const float*)d_in[4];
    const float* bl   = (const float*)d_in[5];
    const int*   edge = (const int*)d_in[6];

    float* out = (float*)d_out;

    // Workspace layout (~19.7 MB)
    int* cntp = (int*)d_ws;                          // N * 16 (padded, 6.4 MB)
    int* off  = cntp + (size_t)N_NODES * CPAD;       // N
    int* bsum = off + N_NODES;                       // 128
    int* rank = bsum + 128;                          // E (6.4 MB)
    int* scol = rank + N_EDGES;                      // E (6.4 MB)

    hipMemsetAsync(cntp, 0, (size_t)N_NODES * CPAD * sizeof(int), stream);

    const int eblk = (N_EDGES + 255) / 256;          // 6250
    rank_kernel<<<eblk, 256, 0, stream>>>(edge, cntp, rank);
    scan_reduce_kernel<<<SCAN_NBLK, SCAN_BS, 0, stream>>>(cntp, bsum);
    scan_top_kernel<<<1, 128, 0, stream>>>(bsum);
    scan_down_kernel<<<SCAN_NBLK, SCAN_BS, 0, stream>>>(cntp, bsum, off);
    scatter_kernel<<<eblk, 256, 0, stream>>>(edge, rank, off, scol);
    node_kernel<<<N_NODES / 4, 256, 0, stream>>>(
        x, curv, off, scol, Wc, bc, Wl, bl, out);
}